// Round 1
// baseline (92.854 us; speedup 1.0000x reference)
//
#include <hip/hip_runtime.h>

// R11: delete the interior LDS pipeline entirely — direct global->reg->store
// 17-tap conv with float4 vector accumulation.
//
// R10 post-mortem: kernel ~28.8us (bench 87.8 - ~59us fixed harness overhead)
// vs ~10.6us HBM roofline (67MB @ 6.3TB/s). rocprof top-k showed only the
// harness's 268MB re-poison fills (44us each, 72-77% HBM) — side-effect: L3 is
// cold for us every iteration. The residual ~18us is the conv path's LDS
// structure: ~2650 LDS-pipe cycles/block (stage transpose + b128 reads +
// epilogue transpose) serialized on the per-CU LDS unit, phase-locked by 3
// __syncthreads with only 4 resident blocks/CU, so VMEM/LDS/VALU pipes
// alternate instead of overlapping.
//
// R11 structure: the stencil is along rows of an (N,8) f32 array, so a thread
// owning one float4 half-row (cols 0-3 or 4-7) x 8 consecutive rows computes
// the conv as float4 FMAs straight from global: 24 float4 loads -> 136 float4
// FMA -> 8 float4 stores. No LDS, no barriers, no transpose. Per wave
// instruction, loads cover 32 row-strips at 256B stride; the unrolled m-loop
// consumes every 64B line fully, so HBM fetch stays ~1x and the 3x
// inter-thread halo overlap hits L1/L2 (working set ~8KB/wave).
// Edge blocks (literal-sweep, R7-R10 validated) unchanged.

namespace {
constexpr int kN = 1048576;
constexpr int kSweeps = 32;  // NUM_ITERATION + 1
constexpr int kThreads = 512;

// --- conv path ---
constexpr int kR = 8;                 // tap radius (17 taps)
constexpr int kTaps = 2 * kR + 1;
constexpr int kKOut = 8;              // output rows per thread
constexpr int kRowsPerBlock = (kThreads / 2) * kKOut;  // 2048
constexpr int kEdgeRows = 512;        // rows owned by each edge block
constexpr int kConvRows = kN - 2 * kEdgeRows;          // 1047552
constexpr int kConvBlocks =
    (kConvRows + kRowsPerBlock - 1) / kRowsPerBlock;   // 512 (last partial)

// --- edge (literal sweep) path, validated R7-R10 ---
constexpr int kTileE = 512;
constexpr int kHaloE = 64;                  // 2 rows/sweep * 32 sweeps
constexpr int kRegE = kTileE + 2 * kHaloE;  // 640 region rows
constexpr int kS = kRegE / 64;              // 10 rows per lane
constexpr int kPad = 9;                     // row-major pad for edge staging
constexpr float kC1 = 0.005f;               // ni * (1 - beta)
constexpr float kC2 = 0.005f;               // ni * beta

constexpr int kSmemFloats = kRegE * kPad;   // 5760 floats = 23,040 B

// ---- Compile-time weights: W = A^32 + c2 * sum_{k=0}^{31} A^k, center 17 ----
struct WF {
  float w[kTaps];
};
constexpr WF make_w() {
  const double ni = (double)0.01f;
  const double c1 = ni * 0.5;
  const double c2 = ni * 0.5;
  double p[129] = {};  // current A^k row (symmetric operator)
  double s[129] = {};  // sum of A^k, k=0..31
  p[64] = 1.0;
  for (int k = 0; k < kSweeps; ++k) {
    for (int i = 0; i < 129; ++i) s[i] += p[i];
    double q[129] = {};
    for (int i = 0; i < 129; ++i) {
      const double m2 = (i > 1) ? p[i - 2] : 0.0;
      const double m1 = (i > 0) ? p[i - 1] : 0.0;
      const double p1 = (i < 128) ? p[i + 1] : 0.0;
      const double p2 = (i < 127) ? p[i + 2] : 0.0;
      const double lap = m2 - 4.0 * m1 + 6.0 * p[i] - 4.0 * p1 + p2;
      q[i] = p[i] - c1 * lap - c2 * p[i];
    }
    for (int i = 0; i < 129; ++i) p[i] = q[i];
  }
  WF f{};
  for (int i = 0; i < kTaps; ++i) {
    f.w[i] = (float)(p[64 - kR + i] + c2 * s[64 - kR + i]);
  }
  return f;
}
constexpr WF kWT = make_w();
}  // namespace

// ---------------- Interior: direct-from-global 17-tap conv ----------------
__device__ __forceinline__ void run_conv(const float* __restrict__ y,
                                         float* __restrict__ out) {
  const int t = (int)threadIdx.x;
  const int half = t & 1;   // float4 half-row: cols 0-3 or 4-7
  const int jb = t >> 1;    // row-strip index within block, 0..255
  const long r0 = (long)kEdgeRows + ((long)blockIdx.x - 1) * kRowsPerBlock +
                  (long)jb * kKOut;
  if (r0 >= (long)(kN - kEdgeRows)) return;  // last conv block is half-empty

  // Input window: rows [r0-8, r0+kKOut+8). Row r = float4s {2r, 2r+1}.
  const float4* __restrict__ src = (const float4*)y + ((r0 - kR) * 2 + half);

  float4 acc[kKOut];
#pragma unroll
  for (int k = 0; k < kKOut; ++k) acc[k] = make_float4(0.f, 0.f, 0.f, 0.f);

#pragma unroll
  for (int m = 0; m < kKOut + 2 * kR; ++m) {  // 24 streamed loads
    const float4 x = src[2 * m];              // row r0-8+m, this half
#pragma unroll
    for (int k = 0; k < kKOut; ++k) {
      const int d = m - k;  // tap index; offset d-8 in [-8,8]
      if (d >= 0 && d < kTaps) {
        const float w = kWT.w[d];
        acc[k].x = fmaf(w, x.x, acc[k].x);
        acc[k].y = fmaf(w, x.y, acc[k].y);
        acc[k].z = fmaf(w, x.z, acc[k].z);
        acc[k].w = fmaf(w, x.w, acc[k].w);
      }
    }
  }

  float4* __restrict__ dst = (float4*)out + (r0 * 2 + half);
#pragma unroll
  for (int k = 0; k < kKOut; ++k) {
    dst[2 * k] = acc[k];
  }
}

// ------------- Edge blocks: literal 32 sweeps (R7-R10 path) -------------
__device__ __forceinline__ void run_edge(const float* __restrict__ y,
                                         float* __restrict__ out,
                                         float* __restrict__ st,
                                         long base_out) {
  const int tid = (int)threadIdx.x;
  const int w = tid >> 6;  // wave id == column
  const int l = tid & 63;  // lane == row segment (rows kS*l .. kS*l+9)
  const long base = base_out - kHaloE;  // region row 0 (may be <0 or >N-640)

  // Stage y row-major (pad-9), guarded.
#pragma unroll
  for (int k = 0; k < 5; ++k) {
    const int idx = (tid + k * kThreads) * 2;  // 5120 floats = 640*8
    const int r = idx >> 3, c = idx & 7;
    const long gi = base + r;
    float2 v = make_float2(0.0f, 0.0f);
    if (gi >= 0 && gi < kN) v = *(const float2*)&y[gi * 8 + c];
    st[r * kPad + c] = v.x;
    st[r * kPad + c + 1] = v.y;
  }
  __syncthreads();

  float buf[kS];
  float ky[kS];
#pragma unroll
  for (int r = 0; r < kS; ++r) {
    const float v = st[(l * kS + r) * kPad + w];
    buf[r] = v;
    ky[r] = kC2 * v;
  }

  for (int s = 0; s < kSweeps; ++s) {
    const float om2_0 = __shfl_up(buf[kS - 2], 1, 64);
    const float om1_0 = __shfl_up(buf[kS - 1], 1, 64);
    const float hp1 = __shfl_down(buf[0], 1, 64);
    const float hp2 = __shfl_down(buf[1], 1, 64);
    float om2 = om2_0, om1 = om1_0;
#pragma unroll
    for (int r = 0; r < kS; ++r) {
      const float o0 = buf[r];
      const float d1 = (r < kS - 1) ? buf[r + 1] : hp1;
      const float d2 = (r < kS - 2) ? buf[r + 2] : ((r == kS - 2) ? hp1 : hp2);
      const long gi = base + l * kS + r;
      const int lr = l * kS + r;
      float lap = om2 - 4.0f * om1 + 6.0f * o0 - 4.0f * d1 + d2;
      if (gi == 1) lap = -2.0f * om1 + 5.0f * o0 - 4.0f * d1 + d2;
      const float t = fmaf(-kC2, o0, o0) + ky[r];
      float nv = fmaf(-kC1, lap, t);
      const bool frozen =
          (gi <= 0) || (gi >= kN - 2) || (lr < 2) || (lr >= kRegE - 2);
      if (frozen) nv = o0;
      buf[r] = nv;
      om2 = om1;
      om1 = o0;
    }
  }

  __syncthreads();
#pragma unroll
  for (int r = 0; r < kS; ++r) {
    st[(l * kS + r) * kPad + w] = buf[r];
  }
  __syncthreads();
#pragma unroll
  for (int k = 0; k < 4; ++k) {
    const int idx = (tid + k * kThreads) * 2;  // 4096 valid floats
    const int r = idx >> 3, c = idx & 7;
    float2 v;
    v.x = st[(kHaloE + r) * kPad + c];
    v.y = st[(kHaloE + r) * kPad + c + 1];
    *(float2*)&out[(base + kHaloE + r) * 8 + c] = v;
  }
}

__global__ __launch_bounds__(kThreads, 4) void biharm_kernel(
    const float* __restrict__ y, float* __restrict__ out) {
  __shared__ __align__(16) float sm[kSmemFloats];  // edge path only, 23 KB
  // Branch is block-uniform -> __syncthreads inside run_edge is safe.
  if (blockIdx.x == 0) {
    run_edge(y, out, sm, 0);
  } else if (blockIdx.x == (int)gridDim.x - 1) {
    run_edge(y, out, sm, (long)kN - kTileE);
  } else {
    run_conv(y, out);
  }
}

extern "C" void kernel_launch(void* const* d_in, const int* in_sizes, int n_in,
                              void* d_out, int out_size, void* d_ws,
                              size_t ws_size, hipStream_t stream) {
  const float* yp = (const float*)d_in[0];
  float* outp = (float*)d_out;
  // 512 conv blocks of 2048 rows covering [512, N-512) (last half-active)
  // + 2 edge blocks.
  biharm_kernel<<<dim3(kConvBlocks + 2), dim3(kThreads), 0, stream>>>(yp, outp);
}

// Round 3
// 87.507 us; speedup vs baseline: 1.0611x; 1.0611x over previous
//
#include <hip/hip_runtime.h>

// R13: resubmit of R12 (infra failure: "MI355X container failed twice", no
// counters returned). Only change: __launch_bounds__ min-waves 6 -> 4 (the
// R11-proven value) to rule out forced-low-VGPR spills as a confound.
//
// R12 design: software-pipelined conv tiles — stage tile t+1 into registers
// while computing/storing tile t (T14 issue-early/write-late), keeping R10's
// fully-coalesced VMEM pattern.
//
// R11 post-mortem: direct-global conv REGRESSED (87.8 -> 92.9us). Each wave
// VMEM instr was 32 discontiguous 32B segments (thread-owns-8-rows layout);
// ~12K segment transactions/CU vs ~600 coalesced -> TA/L2 request rate bound,
// not HBM bytes (fills in the same run hit 6.3TB/s). Lesson: per-instruction
// segment count matters as much as total bytes.
//
// R10 residual theory (~29us vs 10.6us roofline): phase serialization.
// burst-load -> barrier -> compute -> barrier -> store, with every resident
// block parked at the same vmcnt(0)+barrier drain. R12/R13: each conv block
// processes 4 tiles of 512 rows; the guarded float4 loads of tile t+1 are
// issued right after tile t's LDS transpose-writes (first use of those regs
// is next iteration's ds_write, so the compiler's vmcnt wait lands there) —
// HBM read latency + read stream hide under compute + epilogue + stores.
// Edge blocks (literal-sweep, R7-R10 validated) unchanged.

namespace {
constexpr int kN = 1048576;
constexpr int kSweeps = 32;  // NUM_ITERATION + 1
constexpr int kThreads = 512;

// --- conv path ---
constexpr int kR = 8;                       // tap radius (17 taps)
constexpr int kTaps = 2 * kR + 1;
constexpr int kTileC = 512;                 // output rows per conv tile
constexpr int kHaloC = 16;                  // staged halo (float4-friendly)
constexpr int kRegC = kTileC + 2 * kHaloC;  // 544 region rows
constexpr int kColS = 548;                  // LDS col stride (floats)
constexpr int kTPB = 4;                     // tiles per conv block (pipelined)
constexpr int kEdgeRows = 512;
constexpr int kConvTiles = (kN - 2 * kEdgeRows) / kTileC;  // 2046
constexpr int kConvBlocks = (kConvTiles + kTPB - 1) / kTPB;  // 512
constexpr int kStg = (kRegC * 8 / 4 + kThreads - 1) / kThreads;  // 3 float4

// --- edge (literal sweep) path, validated R7-R11 ---
constexpr int kTileE = 512;
constexpr int kHaloE = 64;                  // 2 rows/sweep * 32 sweeps
constexpr int kRegE = kTileE + 2 * kHaloE;  // 640 region rows
constexpr int kS = kRegE / 64;              // 10 rows per lane
constexpr int kPad = 9;                     // row-major pad for edge staging
constexpr float kC1 = 0.005f;               // ni * (1 - beta)
constexpr float kC2 = 0.005f;               // ni * beta

// max(edge 640*9 = 5760, conv 8*548 = 4384) floats
constexpr int kSmemFloats = kRegE * kPad;   // 5760 floats = 23,040 B

// ---- Compile-time weights: W = A^32 + c2 * sum_{k=0}^{31} A^k, center 17 ----
struct WF {
  float w[kTaps];
};
constexpr WF make_w() {
  const double ni = (double)0.01f;
  const double c1 = ni * 0.5;
  const double c2 = ni * 0.5;
  double p[129] = {};  // current A^k row (symmetric operator)
  double s[129] = {};  // sum of A^k, k=0..31
  p[64] = 1.0;
  for (int k = 0; k < kSweeps; ++k) {
    for (int i = 0; i < 129; ++i) s[i] += p[i];
    double q[129] = {};
    for (int i = 0; i < 129; ++i) {
      const double m2 = (i > 1) ? p[i - 2] : 0.0;
      const double m1 = (i > 0) ? p[i - 1] : 0.0;
      const double p1 = (i < 128) ? p[i + 1] : 0.0;
      const double p2 = (i < 127) ? p[i + 2] : 0.0;
      const double lap = m2 - 4.0 * m1 + 6.0 * p[i] - 4.0 * p1 + p2;
      q[i] = p[i] - c1 * lap - c2 * p[i];
    }
    for (int i = 0; i < 129; ++i) p[i] = q[i];
  }
  WF f{};
  for (int i = 0; i < kTaps; ++i) {
    f.w[i] = (float)(p[64 - kR + i] + c2 * s[64 - kR + i]);
  }
  return f;
}
constexpr WF kWT = make_w();
}  // namespace

// Coalesced guarded region load: rows [base-16, base+528), 1088 float4.
__device__ __forceinline__ void stage_load(const float* __restrict__ y,
                                           long base, float4 (&stg)[kStg]) {
  const int tid = (int)threadIdx.x;
#pragma unroll
  for (int k = 0; k < kStg; ++k) {
    const int idx = tid + k * kThreads;
    if (idx < (kRegC * 8) / 4) {
      const int r = idx >> 1;        // region row
      const int cp = (idx & 1) * 4;  // column 0 or 4
      stg[k] = *(const float4*)&y[(base - kHaloC + r) * 8 + cp];
    }
  }
}

// ---------------- Interior: pipelined 17-tap conv, 4 x 512-row tiles --------
__device__ __forceinline__ void run_conv(const float* __restrict__ y,
                                         float* __restrict__ out,
                                         float* __restrict__ sm) {
  const int tid = (int)threadIdx.x;
  const int c = tid & 7;   // column
  const int g = tid >> 3;  // row group (8 rows each), 0..63
  const long tBase = ((long)blockIdx.x - 1) * kTPB;

  float4 stg[kStg];
  stage_load(y, kEdgeRows + tBase * kTileC, stg);

#pragma unroll 1
  for (int t = 0; t < kTPB; ++t) {
    const long tile = tBase + t;
    if (tile >= kConvTiles) break;  // block-uniform
    const long base = kEdgeRows + tile * kTileC;

    if (t) __syncthreads();  // epilogue reads of tile t-1 done

    // Transpose stg -> LDS col-major. (Implicit vmcnt wait lands here.)
#pragma unroll
    for (int k = 0; k < kStg; ++k) {
      const int idx = tid + k * kThreads;
      if (idx < (kRegC * 8) / 4) {
        const int r = idx >> 1;
        const int cp = (idx & 1) * 4;
        sm[(cp + 0) * kColS + r] = stg[k].x;
        sm[(cp + 1) * kColS + r] = stg[k].y;
        sm[(cp + 2) * kColS + r] = stg[k].z;
        sm[(cp + 3) * kColS + r] = stg[k].w;
      }
    }
    __syncthreads();

    // Issue next tile's loads NOW — they fly under compute+epilogue+stores.
    if (t + 1 < kTPB && tile + 1 < kConvTiles) {
      stage_load(y, base + kTileC, stg);
    }

    // Thread outputs: region rows 16+8g .. 16+8g+7.
    // Inputs: region rows 8g+8 .. 8g+31 (24 rows, 16B-aligned b128 reads).
    float acc[8];
#pragma unroll
    for (int k = 0; k < 8; ++k) acc[k] = 0.0f;
    const int r0 = g * 8;
    const float* col = &sm[c * kColS + r0 + 8];
#pragma unroll
    for (int q = 0; q < 6; ++q) {
      const float4 x = *(const float4*)&col[4 * q];
      const float xv[4] = {x.x, x.y, x.z, x.w};
#pragma unroll
      for (int i = 0; i < 4; ++i) {
        const int m = 4 * q + i;  // input = region row r0+8+m
#pragma unroll
        for (int k2 = 0; k2 < 8; ++k2) {
          // tap index = m-k2 in [0,16]
          if (m - k2 >= 0 && m - k2 <= 2 * kR) {
            acc[k2] = fmaf(kWT.w[m - k2], xv[i], acc[k2]);
          }
        }
      }
    }

    // Epilogue: transpose through LDS -> fully coalesced float4 stores.
    __syncthreads();  // all fragment reads done before overwrite
#pragma unroll
    for (int k = 0; k < 8; ++k) {
      sm[c * kColS + r0 + k] = acc[k];  // output row r0+k of column c
    }
    __syncthreads();
#pragma unroll
    for (int k = 0; k < 2; ++k) {
      const int idx = tid + k * kThreads;  // 512*8/4 = 1024 float4
      const int r = idx >> 1;
      const int cp = (idx & 1) * 4;
      float4 v;
      v.x = sm[(cp + 0) * kColS + r];
      v.y = sm[(cp + 1) * kColS + r];
      v.z = sm[(cp + 2) * kColS + r];
      v.w = sm[(cp + 3) * kColS + r];
      *(float4*)&out[(base + r) * 8 + cp] = v;
    }
  }
}

// ------------- Edge blocks: literal 32 sweeps (R7-R11 path) -------------
__device__ __forceinline__ void run_edge(const float* __restrict__ y,
                                         float* __restrict__ out,
                                         float* __restrict__ st,
                                         long base_out) {
  const int tid = (int)threadIdx.x;
  const int w = tid >> 6;  // wave id == column
  const int l = tid & 63;  // lane == row segment (rows kS*l .. kS*l+9)
  const long base = base_out - kHaloE;  // region row 0 (may be <0 or >N-640)

  // Stage y row-major (pad-9), guarded.
#pragma unroll
  for (int k = 0; k < 5; ++k) {
    const int idx = (tid + k * kThreads) * 2;  // 5120 floats = 640*8
    const int r = idx >> 3, c = idx & 7;
    const long gi = base + r;
    float2 v = make_float2(0.0f, 0.0f);
    if (gi >= 0 && gi < kN) v = *(const float2*)&y[gi * 8 + c];
    st[r * kPad + c] = v.x;
    st[r * kPad + c + 1] = v.y;
  }
  __syncthreads();

  float buf[kS];
  float ky[kS];
#pragma unroll
  for (int r = 0; r < kS; ++r) {
    const float v = st[(l * kS + r) * kPad + w];
    buf[r] = v;
    ky[r] = kC2 * v;
  }

  for (int s = 0; s < kSweeps; ++s) {
    const float om2_0 = __shfl_up(buf[kS - 2], 1, 64);
    const float om1_0 = __shfl_up(buf[kS - 1], 1, 64);
    const float hp1 = __shfl_down(buf[0], 1, 64);
    const float hp2 = __shfl_down(buf[1], 1, 64);
    float om2 = om2_0, om1 = om1_0;
#pragma unroll
    for (int r = 0; r < kS; ++r) {
      const float o0 = buf[r];
      const float d1 = (r < kS - 1) ? buf[r + 1] : hp1;
      const float d2 = (r < kS - 2) ? buf[r + 2] : ((r == kS - 2) ? hp1 : hp2);
      const long gi = base + l * kS + r;
      const int lr = l * kS + r;
      float lap = om2 - 4.0f * om1 + 6.0f * o0 - 4.0f * d1 + d2;
      if (gi == 1) lap = -2.0f * om1 + 5.0f * o0 - 4.0f * d1 + d2;
      const float t = fmaf(-kC2, o0, o0) + ky[r];
      float nv = fmaf(-kC1, lap, t);
      const bool frozen =
          (gi <= 0) || (gi >= kN - 2) || (lr < 2) || (lr >= kRegE - 2);
      if (frozen) nv = o0;
      buf[r] = nv;
      om2 = om1;
      om1 = o0;
    }
  }

  __syncthreads();
#pragma unroll
  for (int r = 0; r < kS; ++r) {
    st[(l * kS + r) * kPad + w] = buf[r];
  }
  __syncthreads();
#pragma unroll
  for (int k = 0; k < 4; ++k) {
    const int idx = (tid + k * kThreads) * 2;  // 4096 valid floats
    const int r = idx >> 3, c = idx & 7;
    float2 v;
    v.x = st[(kHaloE + r) * kPad + c];
    v.y = st[(kHaloE + r) * kPad + c + 1];
    *(float2*)&out[(base + kHaloE + r) * 8 + c] = v;
  }
}

__global__ __launch_bounds__(kThreads, 4) void biharm_kernel(
    const float* __restrict__ y, float* __restrict__ out) {
  __shared__ __align__(16) float sm[kSmemFloats];  // 23,040 B
  // Branch is block-uniform -> __syncthreads inside is safe.
  if (blockIdx.x == 0) {
    run_edge(y, out, sm, 0);
  } else if (blockIdx.x == (int)gridDim.x - 1) {
    run_edge(y, out, sm, (long)kN - kTileE);
  } else {
    run_conv(y, out, sm);
  }
}

extern "C" void kernel_launch(void* const* d_in, const int* in_sizes, int n_in,
                              void* d_out, int out_size, void* d_ws,
                              size_t ws_size, hipStream_t stream) {
  const float* yp = (const float*)d_in[0];
  float* outp = (float*)d_out;
  // 512 conv blocks x 4 pipelined tiles of 512 rows covering [512, N-512)
  // + 2 edge blocks.
  biharm_kernel<<<dim3(kConvBlocks + 2), dim3(kThreads), 0, stream>>>(yp, outp);
}

// Round 4
// 86.471 us; speedup vs baseline: 1.0738x; 1.0120x over previous
//
#include <hip/hip_runtime.h>

// R14: many small independent conv blocks (256-row tiles, kTPB=1) instead of
// pipelining inside big barrier-locked blocks.
//
// R13 post-mortem: intra-block software pipelining was NEUTRAL (87.5 vs
// 87.8us). With R11 (-5us) the record reads: coalescing matters, explicit
// pipelining ~0. Cycle budget per CU (HBM 10.6us, LDS ~6-8us — the b128
// col-major reads are bank-BALANCED (8 words/bank/instr = structural floor),
// VALU ~4.4us) sums to ~21us even fully serialized, less than the assumed
// ~29us kernel. Surviving theories: (a) harness floor is >59us and the kernel
// is already ~15-20us; (b) too few independent barrier groups per CU (2-4
// blocks of 512 threads) -> VMEM/LDS/VALU pipes ping-pong in lockstep and
// intra-block pipelining can't help because the barrier drains vmcnt anyway.
//
// R14 tests (b): 4092 conv blocks of 256 rows, ~4 blocks/CU x ~4 ragged
// rounds — resident blocks naturally sit in different phases, each barrier
// gangs only 8 of ~32 resident waves. Smaller per-thread state (acc[4],
// stg[2]) -> VGPR ~48 -> 4 blocks/CU. Halo refetch 6%->12.5% (+0.3us
// roofline) buys the raggedness. Edge blocks (unchanged, validated R7-R13
// 512-thread path) moved to blockIdx 0/1 so they start in round 1.
// If neutral: theory (a) confirmed -> declare roofline.

namespace {
constexpr int kN = 1048576;
constexpr int kSweeps = 32;  // NUM_ITERATION + 1
constexpr int kThreads = 512;

// --- conv path ---
constexpr int kR = 8;                       // tap radius (17 taps)
constexpr int kTaps = 2 * kR + 1;
constexpr int kTileC = 256;                 // output rows per conv tile
constexpr int kHaloC = 16;                  // staged halo (float4-friendly)
constexpr int kRegC = kTileC + 2 * kHaloC;  // 288 region rows
constexpr int kColS = kRegC + 4;            // 292: LDS col stride (floats)
constexpr int kRowsPT = 4;                  // output rows per thread
constexpr int kEdgeRows = 512;
constexpr int kConvTiles = (kN - 2 * kEdgeRows) / kTileC;  // 4092

// --- edge (literal sweep) path, validated R7-R13 ---
constexpr int kTileE = 512;
constexpr int kHaloE = 64;                  // 2 rows/sweep * 32 sweeps
constexpr int kRegE = kTileE + 2 * kHaloE;  // 640 region rows
constexpr int kS = kRegE / 64;              // 10 rows per lane
constexpr int kPad = 9;                     // row-major pad for edge staging
constexpr float kC1 = 0.005f;               // ni * (1 - beta)
constexpr float kC2 = 0.005f;               // ni * beta

// max(edge 640*9 = 5760, conv 8*292 = 2336) floats
constexpr int kSmemFloats = kRegE * kPad;   // 5760 floats = 23,040 B

// ---- Compile-time weights: W = A^32 + c2 * sum_{k=0}^{31} A^k, center 17 ----
struct WF {
  float w[kTaps];
};
constexpr WF make_w() {
  const double ni = (double)0.01f;
  const double c1 = ni * 0.5;
  const double c2 = ni * 0.5;
  double p[129] = {};  // current A^k row (symmetric operator)
  double s[129] = {};  // sum of A^k, k=0..31
  p[64] = 1.0;
  for (int k = 0; k < kSweeps; ++k) {
    for (int i = 0; i < 129; ++i) s[i] += p[i];
    double q[129] = {};
    for (int i = 0; i < 129; ++i) {
      const double m2 = (i > 1) ? p[i - 2] : 0.0;
      const double m1 = (i > 0) ? p[i - 1] : 0.0;
      const double p1 = (i < 128) ? p[i + 1] : 0.0;
      const double p2 = (i < 127) ? p[i + 2] : 0.0;
      const double lap = m2 - 4.0 * m1 + 6.0 * p[i] - 4.0 * p1 + p2;
      q[i] = p[i] - c1 * lap - c2 * p[i];
    }
    for (int i = 0; i < 129; ++i) p[i] = q[i];
  }
  WF f{};
  for (int i = 0; i < kTaps; ++i) {
    f.w[i] = (float)(p[64 - kR + i] + c2 * s[64 - kR + i]);
  }
  return f;
}
constexpr WF kWT = make_w();
}  // namespace

// ---------------- Interior: 17-tap conv, one 256-row tile per block ---------
__device__ __forceinline__ void run_conv(const float* __restrict__ y,
                                         float* __restrict__ out,
                                         float* __restrict__ sm) {
  const int tid = (int)threadIdx.x;
  const int c = tid & 7;   // column
  const int g = tid >> 3;  // row group (4 rows each), 0..63
  const long tile = (long)blockIdx.x - 2;
  const long base = kEdgeRows + tile * kTileC;

  // Stage region rows [base-16, base+272) col-major: 288*8 = 576 float4.
  float4 stg[2];
#pragma unroll
  for (int k = 0; k < 2; ++k) {
    const int idx = tid + k * kThreads;
    if (idx < (kRegC * 8) / 4) {
      const int r = idx >> 1;        // region row
      const int cp = (idx & 1) * 4;  // column 0 or 4
      stg[k] = *(const float4*)&y[(base - kHaloC + r) * 8 + cp];
    }
  }
#pragma unroll
  for (int k = 0; k < 2; ++k) {
    const int idx = tid + k * kThreads;
    if (idx < (kRegC * 8) / 4) {
      const int r = idx >> 1;
      const int cp = (idx & 1) * 4;
      sm[(cp + 0) * kColS + r] = stg[k].x;
      sm[(cp + 1) * kColS + r] = stg[k].y;
      sm[(cp + 2) * kColS + r] = stg[k].z;
      sm[(cp + 3) * kColS + r] = stg[k].w;
    }
  }
  __syncthreads();

  // Thread outputs: region rows 16+4g .. 16+4g+3.
  // Inputs: region rows 4g+8 .. 4g+27 (20 rows, 16B-aligned b128 reads).
  float acc[kRowsPT];
#pragma unroll
  for (int k = 0; k < kRowsPT; ++k) acc[k] = 0.0f;
  const int r0 = g * kRowsPT;
  const float* col = &sm[c * kColS + r0 + 8];
#pragma unroll
  for (int q = 0; q < 5; ++q) {
    const float4 x = *(const float4*)&col[4 * q];
    const float xv[4] = {x.x, x.y, x.z, x.w};
#pragma unroll
    for (int i = 0; i < 4; ++i) {
      const int m = 4 * q + i;  // input = region row r0+8+m
#pragma unroll
      for (int k2 = 0; k2 < kRowsPT; ++k2) {
        // tap index = m-k2 in [0,16]
        if (m - k2 >= 0 && m - k2 <= 2 * kR) {
          acc[k2] = fmaf(kWT.w[m - k2], xv[i], acc[k2]);
        }
      }
    }
  }

  // Epilogue: transpose through LDS -> fully coalesced float4 stores.
  __syncthreads();  // all fragment reads done before overwrite
#pragma unroll
  for (int k = 0; k < kRowsPT; ++k) {
    sm[c * kColS + r0 + k] = acc[k];  // output row r0+k of column c
  }
  __syncthreads();
  {
    const int idx = tid;  // 256*8/4 = 512 float4, one per thread
    const int r = idx >> 1;
    const int cp = (idx & 1) * 4;
    float4 v;
    v.x = sm[(cp + 0) * kColS + r];
    v.y = sm[(cp + 1) * kColS + r];
    v.z = sm[(cp + 2) * kColS + r];
    v.w = sm[(cp + 3) * kColS + r];
    *(float4*)&out[(base + r) * 8 + cp] = v;
  }
}

// ------------- Edge blocks: literal 32 sweeps (R7-R13 path) -------------
__device__ __forceinline__ void run_edge(const float* __restrict__ y,
                                         float* __restrict__ out,
                                         float* __restrict__ st,
                                         long base_out) {
  const int tid = (int)threadIdx.x;
  const int w = tid >> 6;  // wave id == column
  const int l = tid & 63;  // lane == row segment (rows kS*l .. kS*l+9)
  const long base = base_out - kHaloE;  // region row 0 (may be <0 or >N-640)

  // Stage y row-major (pad-9), guarded.
#pragma unroll
  for (int k = 0; k < 5; ++k) {
    const int idx = (tid + k * kThreads) * 2;  // 5120 floats = 640*8
    const int r = idx >> 3, c = idx & 7;
    const long gi = base + r;
    float2 v = make_float2(0.0f, 0.0f);
    if (gi >= 0 && gi < kN) v = *(const float2*)&y[gi * 8 + c];
    st[r * kPad + c] = v.x;
    st[r * kPad + c + 1] = v.y;
  }
  __syncthreads();

  float buf[kS];
  float ky[kS];
#pragma unroll
  for (int r = 0; r < kS; ++r) {
    const float v = st[(l * kS + r) * kPad + w];
    buf[r] = v;
    ky[r] = kC2 * v;
  }

  for (int s = 0; s < kSweeps; ++s) {
    const float om2_0 = __shfl_up(buf[kS - 2], 1, 64);
    const float om1_0 = __shfl_up(buf[kS - 1], 1, 64);
    const float hp1 = __shfl_down(buf[0], 1, 64);
    const float hp2 = __shfl_down(buf[1], 1, 64);
    float om2 = om2_0, om1 = om1_0;
#pragma unroll
    for (int r = 0; r < kS; ++r) {
      const float o0 = buf[r];
      const float d1 = (r < kS - 1) ? buf[r + 1] : hp1;
      const float d2 = (r < kS - 2) ? buf[r + 2] : ((r == kS - 2) ? hp1 : hp2);
      const long gi = base + l * kS + r;
      const int lr = l * kS + r;
      float lap = om2 - 4.0f * om1 + 6.0f * o0 - 4.0f * d1 + d2;
      if (gi == 1) lap = -2.0f * om1 + 5.0f * o0 - 4.0f * d1 + d2;
      const float t = fmaf(-kC2, o0, o0) + ky[r];
      float nv = fmaf(-kC1, lap, t);
      const bool frozen =
          (gi <= 0) || (gi >= kN - 2) || (lr < 2) || (lr >= kRegE - 2);
      if (frozen) nv = o0;
      buf[r] = nv;
      om2 = om1;
      om1 = o0;
    }
  }

  __syncthreads();
#pragma unroll
  for (int r = 0; r < kS; ++r) {
    st[(l * kS + r) * kPad + w] = buf[r];
  }
  __syncthreads();
#pragma unroll
  for (int k = 0; k < 4; ++k) {
    const int idx = (tid + k * kThreads) * 2;  // 4096 valid floats
    const int r = idx >> 3, c = idx & 7;
    float2 v;
    v.x = st[(kHaloE + r) * kPad + c];
    v.y = st[(kHaloE + r) * kPad + c + 1];
    *(float2*)&out[(base + kHaloE + r) * 8 + c] = v;
  }
}

__global__ __launch_bounds__(kThreads) void biharm_kernel(
    const float* __restrict__ y, float* __restrict__ out) {
  __shared__ __align__(16) float sm[kSmemFloats];  // 23,040 B
  // Branch is block-uniform -> __syncthreads inside is safe.
  // Edge blocks first so they start in scheduling round 1.
  if (blockIdx.x == 0) {
    run_edge(y, out, sm, 0);
  } else if (blockIdx.x == 1) {
    run_edge(y, out, sm, (long)kN - kTileE);
  } else {
    run_conv(y, out, sm);
  }
}

extern "C" void kernel_launch(void* const* d_in, const int* in_sizes, int n_in,
                              void* d_out, int out_size, void* d_ws,
                              size_t ws_size, hipStream_t stream) {
  const float* yp = (const float*)d_in[0];
  float* outp = (float*)d_out;
  // 2 edge blocks + 4092 conv tiles of 256 rows covering [512, N-512).
  biharm_kernel<<<dim3(kConvTiles + 2), dim3(kThreads), 0, stream>>>(yp, outp);
}